// Round 2
// baseline (1873.477 us; speedup 1.0000x reference)
//
#include <hip/hip_runtime.h>
#include <hip/hip_bf16.h>

// Problem constants
#define BB   2
#define SEQ  2048
#define DIMD 2048
#define NHH  32
#define NKVV 8
#define HDD  64
// N_REP = 4

typedef __bf16 bf16x8 __attribute__((ext_vector_type(8)));
typedef float  floatx4 __attribute__((ext_vector_type(4)));

__device__ __forceinline__ float bf2f(unsigned short u) {
    union { unsigned int i; float f; } v; v.i = ((unsigned int)u) << 16; return v.f;
}

// ---------------------------------------------------------------------------
// f32 -> bf16 conversion (vectorized by 4)
// ---------------------------------------------------------------------------
__global__ void cvt_f32_bf16(const float* __restrict__ in, __hip_bfloat16* __restrict__ out, int n) {
    int i = (blockIdx.x * blockDim.x + threadIdx.x) * 4;
    if (i >= n) return;
    float4 v = *reinterpret_cast<const float4*>(in + i);
    out[i + 0] = __float2bfloat16(v.x);
    out[i + 1] = __float2bfloat16(v.y);
    out[i + 2] = __float2bfloat16(v.z);
    out[i + 3] = __float2bfloat16(v.w);
}

// ---------------------------------------------------------------------------
// GEMM: C[M,N] = A[M,K] @ W[N,K]^T   (bf16 in, f32 acc, OutT out)
// block = 256 thr (4 waves), block tile 128x128, wave tile 64x64 (4x4 mfma)
// Direct global fragment loads (no LDS) — correctness-first structure.
// ---------------------------------------------------------------------------
template <typename OutT>
__global__ __launch_bounds__(256) void gemm_bt(
    const __hip_bfloat16* __restrict__ A,
    const __hip_bfloat16* __restrict__ W,
    OutT* __restrict__ C,
    int M, int N, int K)
{
    const __bf16* a = reinterpret_cast<const __bf16*>(A);
    const __bf16* w = reinterpret_cast<const __bf16*>(W);

    int wid  = threadIdx.x >> 6;
    int lane = threadIdx.x & 63;
    int wm = (wid & 1) * 64;
    int wn = (wid >> 1) * 64;
    int bm = blockIdx.x * 128;
    int bn = blockIdx.y * 128;
    int l15 = lane & 15;
    int l4  = lane >> 4;

    floatx4 acc[4][4] = {};

    for (int k0 = 0; k0 < K; k0 += 32) {
        int kk = k0 + l4 * 8;
        bf16x8 af[4], bfr[4];
        #pragma unroll
        for (int i = 0; i < 4; ++i)
            af[i] = *reinterpret_cast<const bf16x8*>(a + (size_t)(bm + wm + i * 16 + l15) * K + kk);
        #pragma unroll
        for (int j = 0; j < 4; ++j)
            bfr[j] = *reinterpret_cast<const bf16x8*>(w + (size_t)(bn + wn + j * 16 + l15) * K + kk);
        #pragma unroll
        for (int i = 0; i < 4; ++i)
            #pragma unroll
            for (int j = 0; j < 4; ++j)
                acc[i][j] = __builtin_amdgcn_mfma_f32_16x16x32_bf16(af[i], bfr[j], acc[i][j], 0, 0, 0);
    }

    #pragma unroll
    for (int i = 0; i < 4; ++i)
        #pragma unroll
        for (int j = 0; j < 4; ++j)
            #pragma unroll
            for (int r = 0; r < 4; ++r) {
                int row = bm + wm + i * 16 + l4 * 4 + r;
                int col = bn + wn + j * 16 + l15;
                if constexpr (sizeof(OutT) == 4)
                    C[(size_t)row * N + col] = acc[i][j][r];
                else
                    C[(size_t)row * N + col] = __float2bfloat16(acc[i][j][r]);
            }
}

// ---------------------------------------------------------------------------
// RoPE (in-place on q or k buffer laid out [B*S][heads*64], bf16)
// pair (d, d+32) within each head; f32 cos/sin indexed [s][d], d<32
// ---------------------------------------------------------------------------
__global__ void rope_kernel(__hip_bfloat16* buf,
                            const float* __restrict__ cosb,
                            const float* __restrict__ sinb,
                            int heads)
{
    int idx = blockIdx.x * blockDim.x + threadIdx.x;
    int total = (BB * SEQ) * heads * 32;
    if (idx >= total) return;
    int d   = idx & 31;
    int h   = (idx >> 5) % heads;
    int row = idx / (heads * 32);
    int s   = row & (SEQ - 1);
    size_t base = (size_t)row * (heads * 64) + h * 64 + d;
    float x1 = __bfloat162float(buf[base]);
    float x2 = __bfloat162float(buf[base + 32]);
    float c  = cosb[s * 32 + d];
    float sn = sinb[s * 32 + d];
    buf[base]      = __float2bfloat16(x1 * c - x2 * sn);
    buf[base + 32] = __float2bfloat16(x2 * c + x1 * sn);
}

// ---------------------------------------------------------------------------
// Flash attention with doc + causal mask.
// grid (S/64, NH, B), block 256. 64 queries per block, K/V chunks of 64.
// Thread t: query row r = t>>2 (0..63), sub-lane c = t&3.
//   scores: thread computes j in {jj*4+c}; PV: thread owns dims [c*16, c*16+16)
// q row held in regs (pre-scaled by 1/8); online softmax, sentinel -1e30.
// ---------------------------------------------------------------------------
__global__ __launch_bounds__(256) void attn_kernel(
    const __hip_bfloat16* __restrict__ qb,   // [B*S][NH*64]
    const __hip_bfloat16* __restrict__ kb,   // [B*S][NKV*64]
    const __hip_bfloat16* __restrict__ vb,   // [B*S][NKV*64]
    const int* __restrict__ doc,             // [B][S]
    __hip_bfloat16* __restrict__ ob)         // [B*S][NH*64]
{
    int qblk = blockIdx.x;
    int h    = blockIdx.y;
    int b    = blockIdx.z;
    int kvh  = h >> 2;           // N_REP = 4
    int tid  = threadIdx.x;
    int r    = tid >> 2;
    int c    = tid & 3;
    int q0   = qblk * 64;

    __shared__ float Ks[64][68];
    __shared__ float Vs[64][68];
    __shared__ float St[64][68];   // staging for Q, then scores->P
    __shared__ int   kdoc[64];

    // stage Q tile into St (scaled by 1/sqrt(HD) = 0.125)
    for (int e = tid; e < 64 * 16; e += 256) {
        int rr = e >> 4, d4 = e & 15;
        ushort4 u = *reinterpret_cast<const ushort4*>(
            qb + (size_t)(b * SEQ + q0 + rr) * (NHH * HDD) + h * HDD + d4 * 4);
        St[rr][d4 * 4 + 0] = 0.125f * bf2f(u.x);
        St[rr][d4 * 4 + 1] = 0.125f * bf2f(u.y);
        St[rr][d4 * 4 + 2] = 0.125f * bf2f(u.z);
        St[rr][d4 * 4 + 3] = 0.125f * bf2f(u.w);
    }
    int qdoc_r = doc[b * SEQ + q0 + r];
    __syncthreads();

    floatx4 qreg[16];
    #pragma unroll
    for (int i = 0; i < 16; ++i)
        qreg[i] = *reinterpret_cast<floatx4*>(&St[r][i * 4]);

    float m = -1e30f, l = 0.f;
    float Ov[16];
    #pragma unroll
    for (int i = 0; i < 16; ++i) Ov[i] = 0.f;
    int dset = c * 16;

    for (int kc = 0; kc <= qblk; ++kc) {
        __syncthreads();   // previous chunk's PV reads done before restage
        int k0 = kc * 64;
        for (int e = tid; e < 64 * 16; e += 256) {
            int rr = e >> 4, d4 = e & 15;
            size_t g = (size_t)(b * SEQ + k0 + rr) * (NKVV * HDD) + kvh * HDD + d4 * 4;
            ushort4 ku = *reinterpret_cast<const ushort4*>(kb + g);
            ushort4 vu = *reinterpret_cast<const ushort4*>(vb + g);
            Ks[rr][d4 * 4 + 0] = bf2f(ku.x);
            Ks[rr][d4 * 4 + 1] = bf2f(ku.y);
            Ks[rr][d4 * 4 + 2] = bf2f(ku.z);
            Ks[rr][d4 * 4 + 3] = bf2f(ku.w);
            Vs[rr][d4 * 4 + 0] = bf2f(vu.x);
            Vs[rr][d4 * 4 + 1] = bf2f(vu.y);
            Vs[rr][d4 * 4 + 2] = bf2f(vu.z);
            Vs[rr][d4 * 4 + 3] = bf2f(vu.w);
        }
        if (tid < 64) kdoc[tid] = doc[b * SEQ + k0 + tid];
        __syncthreads();

        // scores for my 16 keys
        float sc[16];
        float pmax = -1e30f;
        #pragma unroll
        for (int jj = 0; jj < 16; ++jj) {
            int j = jj * 4 + c;
            floatx4 accv = {};
            #pragma unroll
            for (int d4 = 0; d4 < 16; ++d4) {
                floatx4 kv = *reinterpret_cast<floatx4*>(&Ks[j][d4 * 4]);
                accv += qreg[d4] * kv;
            }
            float s = accv[0] + accv[1] + accv[2] + accv[3];
            bool valid = (kdoc[j] == qdoc_r) && ((k0 + j) <= (q0 + r));
            s = valid ? s : -1e30f;
            sc[jj] = s;
            pmax = fmaxf(pmax, s);
        }
        // reduce max over the 4 threads of this row (lanes 4r..4r+3)
        pmax = fmaxf(pmax, __shfl_xor(pmax, 1));
        pmax = fmaxf(pmax, __shfl_xor(pmax, 2));
        float mnew  = fmaxf(m, pmax);
        float alpha = __expf(m - mnew);   // both -1e30 -> 1; stale -1e30 -> 0
        float psum = 0.f;
        #pragma unroll
        for (int jj = 0; jj < 16; ++jj) {
            int j = jj * 4 + c;
            float p = (sc[jj] <= -1e29f) ? 0.f : __expf(sc[jj] - mnew);
            St[r][j] = p;
            psum += p;
        }
        psum += __shfl_xor(psum, 1);
        psum += __shfl_xor(psum, 2);
        l = l * alpha + psum;
        m = mnew;
        #pragma unroll
        for (int i = 0; i < 16; ++i) Ov[i] *= alpha;
        __syncthreads();   // P visible + staging reads done

        // PV: O[r][dset..dset+15] += sum_j P[r][j] * V[j][dset..]
        #pragma unroll 4
        for (int j = 0; j < 64; ++j) {
            float p = St[r][j];
            #pragma unroll
            for (int q4 = 0; q4 < 4; ++q4) {
                floatx4 vv = *reinterpret_cast<floatx4*>(&Vs[j][dset + q4 * 4]);
                Ov[q4 * 4 + 0] += p * vv[0];
                Ov[q4 * 4 + 1] += p * vv[1];
                Ov[q4 * 4 + 2] += p * vv[2];
                Ov[q4 * 4 + 3] += p * vv[3];
            }
        }
    }

    float inv = 1.0f / l;
    #pragma unroll
    for (int i = 0; i < 16; ++i)
        ob[(size_t)(b * SEQ + q0 + r) * (NHH * HDD) + h * HDD + dset + i] =
            __float2bfloat16(Ov[i] * inv);
}

// ---------------------------------------------------------------------------
extern "C" void kernel_launch(void* const* d_in, const int* in_sizes, int n_in,
                              void* d_out, int out_size, void* d_ws, size_t ws_size,
                              hipStream_t stream) {
    const float* x  = (const float*)d_in[0];
    const float* rc = (const float*)d_in[1];
    const float* rs = (const float*)d_in[2];
    const int*   dc = (const int*)d_in[3];
    const float* Wq = (const float*)d_in[4];
    const float* Wk = (const float*)d_in[5];
    const float* Wv = (const float*)d_in[6];
    const float* Wo = (const float*)d_in[7];
    float* out = (float*)d_out;

    const int M = BB * SEQ;          // 4096
    const int KVD = NKVV * HDD;      // 512

    // workspace layout (bf16 buffers)
    char* ws = (char*)d_ws;
    size_t off = 0;
    auto alloc = [&](size_t elems) { __hip_bfloat16* p = (__hip_bfloat16*)(ws + off); off += elems * 2; return p; };
    __hip_bfloat16* xb  = alloc((size_t)M * DIMD);      // 16 MB
    __hip_bfloat16* wqb = alloc((size_t)DIMD * DIMD);   //  8 MB
    __hip_bfloat16* wkb = alloc((size_t)KVD * DIMD);    //  2 MB
    __hip_bfloat16* wvb = alloc((size_t)KVD * DIMD);    //  2 MB
    __hip_bfloat16* wob = alloc((size_t)DIMD * DIMD);   //  8 MB
    __hip_bfloat16* qbuf = alloc((size_t)M * DIMD);     // 16 MB
    __hip_bfloat16* kbuf = alloc((size_t)M * KVD);      //  4 MB
    __hip_bfloat16* vbuf = alloc((size_t)M * KVD);      //  4 MB
    __hip_bfloat16* abuf = alloc((size_t)M * DIMD);     // 16 MB

    // f32 -> bf16 conversions
    auto cvt = [&](const float* src, __hip_bfloat16* dst, size_t n) {
        cvt_f32_bf16<<<dim3((n / 4 + 255) / 256), 256, 0, stream>>>(src, dst, (int)n);
    };
    cvt(x,  xb,  (size_t)M * DIMD);
    cvt(Wq, wqb, (size_t)DIMD * DIMD);
    cvt(Wk, wkb, (size_t)KVD * DIMD);
    cvt(Wv, wvb, (size_t)KVD * DIMD);
    cvt(Wo, wob, (size_t)DIMD * DIMD);

    // QKV projections (bf16 out)
    gemm_bt<__hip_bfloat16><<<dim3(M / 128, DIMD / 128), 256, 0, stream>>>(xb, wqb, qbuf, M, DIMD, DIMD);
    gemm_bt<__hip_bfloat16><<<dim3(M / 128, KVD / 128), 256, 0, stream>>>(xb, wkb, kbuf, M, KVD, DIMD);
    gemm_bt<__hip_bfloat16><<<dim3(M / 128, KVD / 128), 256, 0, stream>>>(xb, wvb, vbuf, M, KVD, DIMD);

    // RoPE on q and k
    {
        int totq = M * NHH * 32;
        rope_kernel<<<(totq + 255) / 256, 256, 0, stream>>>(qbuf, rc, rs, NHH);
        int totk = M * NKVV * 32;
        rope_kernel<<<(totk + 255) / 256, 256, 0, stream>>>(kbuf, rc, rs, NKVV);
    }

    // attention
    attn_kernel<<<dim3(SEQ / 64, NHH, BB), 256, 0, stream>>>(qbuf, kbuf, vbuf, dc, abuf);

    // output projection (f32 out)
    gemm_bt<float><<<dim3(M / 128, DIMD / 128), 256, 0, stream>>>(abuf, wob, out, M, DIMD, DIMD);
}

// Round 3
// 745.816 us; speedup vs baseline: 2.5120x; 2.5120x over previous
//
#include <hip/hip_runtime.h>
#include <hip/hip_bf16.h>

// Problem constants
#define BB   2
#define SEQ  2048
#define DIMD 2048
#define NHH  32
#define NKVV 8
#define HDD  64
// N_REP = 4

typedef __bf16 bf16x8 __attribute__((ext_vector_type(8)));
typedef float  floatx4 __attribute__((ext_vector_type(4)));

__device__ __forceinline__ unsigned short f2bu(float f) {
    __hip_bfloat16 h = __float2bfloat16(f);
    return *reinterpret_cast<unsigned short*>(&h);
}

// ---------------------------------------------------------------------------
// f32 -> bf16 conversion (vectorized by 4)
// ---------------------------------------------------------------------------
__global__ void cvt_f32_bf16(const float* __restrict__ in, __hip_bfloat16* __restrict__ out, int n) {
    int i = (blockIdx.x * blockDim.x + threadIdx.x) * 4;
    if (i >= n) return;
    float4 v = *reinterpret_cast<const float4*>(in + i);
    out[i + 0] = __float2bfloat16(v.x);
    out[i + 1] = __float2bfloat16(v.y);
    out[i + 2] = __float2bfloat16(v.z);
    out[i + 3] = __float2bfloat16(v.w);
}

// ---------------------------------------------------------------------------
// GEMM: C[M,N] = A[M,K] @ W[N,K]^T   (bf16 in, f32 acc, OutT out)
// block = 256 thr (4 waves), block tile 128x128, wave tile 64x64 (4x4 mfma)
// ---------------------------------------------------------------------------
template <typename OutT>
__global__ __launch_bounds__(256) void gemm_bt(
    const __hip_bfloat16* __restrict__ A,
    const __hip_bfloat16* __restrict__ W,
    OutT* __restrict__ C,
    int M, int N, int K)
{
    const __bf16* a = reinterpret_cast<const __bf16*>(A);
    const __bf16* w = reinterpret_cast<const __bf16*>(W);

    int wid  = threadIdx.x >> 6;
    int lane = threadIdx.x & 63;
    int wm = (wid & 1) * 64;
    int wn = (wid >> 1) * 64;
    int bm = blockIdx.x * 128;
    int bn = blockIdx.y * 128;
    int l15 = lane & 15;
    int l4  = lane >> 4;

    floatx4 acc[4][4] = {};

    for (int k0 = 0; k0 < K; k0 += 32) {
        int kk = k0 + l4 * 8;
        bf16x8 af[4], bfr[4];
        #pragma unroll
        for (int i = 0; i < 4; ++i)
            af[i] = *reinterpret_cast<const bf16x8*>(a + (size_t)(bm + wm + i * 16 + l15) * K + kk);
        #pragma unroll
        for (int j = 0; j < 4; ++j)
            bfr[j] = *reinterpret_cast<const bf16x8*>(w + (size_t)(bn + wn + j * 16 + l15) * K + kk);
        #pragma unroll
        for (int i = 0; i < 4; ++i)
            #pragma unroll
            for (int j = 0; j < 4; ++j)
                acc[i][j] = __builtin_amdgcn_mfma_f32_16x16x32_bf16(af[i], bfr[j], acc[i][j], 0, 0, 0);
    }

    #pragma unroll
    for (int i = 0; i < 4; ++i)
        #pragma unroll
        for (int j = 0; j < 4; ++j)
            #pragma unroll
            for (int r = 0; r < 4; ++r) {
                int row = bm + wm + i * 16 + l4 * 4 + r;
                int col = bn + wn + j * 16 + l15;
                if constexpr (sizeof(OutT) == 4)
                    C[(size_t)row * N + col] = acc[i][j][r];
                else
                    C[(size_t)row * N + col] = __float2bfloat16(acc[i][j][r]);
            }
}

// ---------------------------------------------------------------------------
// RoPE (in-place, [B*S][heads*64] bf16); pair (d, d+32); f32 cos/sin [s][d]
// ---------------------------------------------------------------------------
__global__ void rope_kernel(__hip_bfloat16* buf,
                            const float* __restrict__ cosb,
                            const float* __restrict__ sinb,
                            int heads)
{
    int idx = blockIdx.x * blockDim.x + threadIdx.x;
    int total = (BB * SEQ) * heads * 32;
    if (idx >= total) return;
    int d   = idx & 31;
    int h   = (idx >> 5) % heads;
    int row = idx / (heads * 32);
    int s   = row & (SEQ - 1);
    size_t base = (size_t)row * (heads * 64) + h * 64 + d;
    float x1 = __bfloat162float(buf[base]);
    float x2 = __bfloat162float(buf[base + 32]);
    float c  = cosb[s * 32 + d];
    float sn = sinb[s * 32 + d];
    buf[base]      = __float2bfloat16(x1 * c - x2 * sn);
    buf[base + 32] = __float2bfloat16(x2 * c + x1 * sn);
}

// ---------------------------------------------------------------------------
// MFMA flash attention with doc + causal mask.
// grid (S/64, NH, B) with qblk REVERSED for load balance; block 256 (4 waves).
// Wave w owns 16 query rows [q0+16w, q0+16w+16). Per 64-key chunk:
//   QK^T: Q A-frags (global), K B-frags from LDS Ks[key][dim] rows -> 8 mfma
//   softmax in C layout (col=lane&15=key, row=quad*4+reg=query)
//   P -> per-wave LDS tile (A-layout read-back), V staged transposed Vt[dim][key]
//   PV: 8 mfma, O accumulated in C layout with alpha rescale.
// ---------------------------------------------------------------------------
__global__ __launch_bounds__(256) void attn_mfma(
    const __hip_bfloat16* __restrict__ qb,   // [B*S][NH*64]
    const __hip_bfloat16* __restrict__ kb,   // [B*S][NKV*64]
    const __hip_bfloat16* __restrict__ vb,   // [B*S][NKV*64]
    const int* __restrict__ doc,             // [B][S]
    __hip_bfloat16* __restrict__ ob)         // [B*S][NH*64]
{
    int qblk = (int)gridDim.x - 1 - (int)blockIdx.x;   // heavy blocks first
    int h    = blockIdx.y;
    int b    = blockIdx.z;
    int kvh  = h >> 2;           // N_REP = 4
    int tid  = threadIdx.x;
    int wv   = tid >> 6;
    int lane = tid & 63;
    int l15  = lane & 15;
    int l4   = lane >> 4;
    int q0   = qblk * 64;
    int qw   = q0 + wv * 16;     // wave's query base

    // stride 72 elems = 144 B rows: 16B-aligned for b128, 4-bank rotation
    __shared__ unsigned short Ks[64][72];   // [key][dim]
    __shared__ unsigned short Vt[64][72];   // [dim][key]
    __shared__ unsigned short Pb[4][16][72];// per-wave P tile [qrow][key]
    __shared__ int kdoc[64];

    const unsigned short* qus = reinterpret_cast<const unsigned short*>(qb);
    const unsigned short* kus = reinterpret_cast<const unsigned short*>(kb);
    const unsigned short* vus = reinterpret_cast<const unsigned short*>(vb);

    // Q A-fragments: m=l15 (query row), k = l4*8 + j (+32g)
    bf16x8 aq[2];
    {
        const unsigned short* qrow = qus + (size_t)(b * SEQ + qw + l15) * (NHH * HDD) + h * HDD;
        aq[0] = *reinterpret_cast<const bf16x8*>(qrow + l4 * 8);
        aq[1] = *reinterpret_cast<const bf16x8*>(qrow + 32 + l4 * 8);
    }
    int qd[4];
    #pragma unroll
    for (int r = 0; r < 4; ++r) qd[r] = doc[b * SEQ + qw + l4 * 4 + r];

    float mrow[4], lrow[4];
    #pragma unroll
    for (int r = 0; r < 4; ++r) { mrow[r] = -1e30f; lrow[r] = 0.f; }
    floatx4 accO[4] = {};   // [dim tile t]; row=q (l4*4+reg), col=dim (16t+l15)

    int skey = tid >> 2;          // staging: key row
    int scc  = tid & 3;

    for (int kc = 0; kc <= qblk; ++kc) {
        int k0 = kc * 64;
        __syncthreads();   // previous chunk's Vt/Ks reads complete
        {
            const unsigned short* krow = kus + (size_t)(b * SEQ + k0 + skey) * (NKVV * HDD) + kvh * HDD;
            const unsigned short* vrow = vus + (size_t)(b * SEQ + k0 + skey) * (NKVV * HDD) + kvh * HDD;
            #pragma unroll
            for (int it = 0; it < 4; ++it) {
                int d0 = it * 16 + scc * 4;
                ushort4 ku = *reinterpret_cast<const ushort4*>(krow + d0);
                ushort4 vu = *reinterpret_cast<const ushort4*>(vrow + d0);
                *reinterpret_cast<ushort4*>(&Ks[skey][d0]) = ku;
                Vt[d0 + 0][skey] = vu.x;
                Vt[d0 + 1][skey] = vu.y;
                Vt[d0 + 2][skey] = vu.z;
                Vt[d0 + 3][skey] = vu.w;
            }
            if (tid < 64) kdoc[tid] = doc[b * SEQ + k0 + tid];
        }
        __syncthreads();   // staged

        // ---- QK^T: 4 key tiles of 16 ----
        float s[4][4];
        #pragma unroll
        for (int t = 0; t < 4; ++t) {
            bf16x8 bk0 = *reinterpret_cast<const bf16x8*>(&Ks[t * 16 + l15][l4 * 8]);
            bf16x8 bk1 = *reinterpret_cast<const bf16x8*>(&Ks[t * 16 + l15][32 + l4 * 8]);
            floatx4 acc = {};
            acc = __builtin_amdgcn_mfma_f32_16x16x32_bf16(aq[0], bk0, acc, 0, 0, 0);
            acc = __builtin_amdgcn_mfma_f32_16x16x32_bf16(aq[1], bk1, acc, 0, 0, 0);
            int key = k0 + t * 16 + l15;
            int kd  = kdoc[t * 16 + l15];
            #pragma unroll
            for (int r = 0; r < 4; ++r) {
                int qrow = qw + l4 * 4 + r;
                bool valid = (kd == qd[r]) && (key <= qrow);
                s[t][r] = valid ? acc[r] * 0.125f : -1e30f;
            }
        }

        // ---- online softmax per query row (4 rows per lane) ----
        float pval[4][4];
        #pragma unroll
        for (int r = 0; r < 4; ++r) {
            float pm = fmaxf(fmaxf(s[0][r], s[1][r]), fmaxf(s[2][r], s[3][r]));
            pm = fmaxf(pm, __shfl_xor(pm, 1));
            pm = fmaxf(pm, __shfl_xor(pm, 2));
            pm = fmaxf(pm, __shfl_xor(pm, 4));
            pm = fmaxf(pm, __shfl_xor(pm, 8));
            float mnew = fmaxf(mrow[r], pm);
            float alpha = __expf(mrow[r] - mnew);
            mrow[r] = mnew;
            float ps = 0.f;
            #pragma unroll
            for (int t = 0; t < 4; ++t) {
                float p = (s[t][r] <= -1e29f) ? 0.f : __expf(s[t][r] - mnew);
                pval[t][r] = p;
                ps += p;
            }
            ps += __shfl_xor(ps, 1);
            ps += __shfl_xor(ps, 2);
            ps += __shfl_xor(ps, 4);
            ps += __shfl_xor(ps, 8);
            lrow[r] = lrow[r] * alpha + ps;
            #pragma unroll
            for (int t = 0; t < 4; ++t) accO[t][r] *= alpha;
        }

        // ---- P: C layout -> LDS -> A layout ----
        #pragma unroll
        for (int t = 0; t < 4; ++t)
            #pragma unroll
            for (int r = 0; r < 4; ++r)
                Pb[wv][l4 * 4 + r][t * 16 + l15] = f2bu(pval[t][r]);
        __syncthreads();   // P visible (conservative; Pb is per-wave)

        bf16x8 ap0 = *reinterpret_cast<const bf16x8*>(&Pb[wv][l15][l4 * 8]);
        bf16x8 ap1 = *reinterpret_cast<const bf16x8*>(&Pb[wv][l15][32 + l4 * 8]);

        // ---- PV: 4 dim tiles of 16 ----
        #pragma unroll
        for (int t = 0; t < 4; ++t) {
            bf16x8 bv0 = *reinterpret_cast<const bf16x8*>(&Vt[t * 16 + l15][l4 * 8]);
            bf16x8 bv1 = *reinterpret_cast<const bf16x8*>(&Vt[t * 16 + l15][32 + l4 * 8]);
            accO[t] = __builtin_amdgcn_mfma_f32_16x16x32_bf16(ap0, bv0, accO[t], 0, 0, 0);
            accO[t] = __builtin_amdgcn_mfma_f32_16x16x32_bf16(ap1, bv1, accO[t], 0, 0, 0);
        }
    }

    // ---- epilogue ----
    #pragma unroll
    for (int r = 0; r < 4; ++r) {
        float inv = 1.0f / lrow[r];
        size_t base = (size_t)(b * SEQ + qw + l4 * 4 + r) * (NHH * HDD) + h * HDD;
        #pragma unroll
        for (int t = 0; t < 4; ++t)
            ob[base + t * 16 + l15] = __float2bfloat16(accO[t][r] * inv);
    }
}

// ---------------------------------------------------------------------------
extern "C" void kernel_launch(void* const* d_in, const int* in_sizes, int n_in,
                              void* d_out, int out_size, void* d_ws, size_t ws_size,
                              hipStream_t stream) {
    const float* x  = (const float*)d_in[0];
    const float* rc = (const float*)d_in[1];
    const float* rs = (const float*)d_in[2];
    const int*   dc = (const int*)d_in[3];
    const float* Wq = (const float*)d_in[4];
    const float* Wk = (const float*)d_in[5];
    const float* Wv = (const float*)d_in[6];
    const float* Wo = (const float*)d_in[7];
    float* out = (float*)d_out;

    const int M = BB * SEQ;          // 4096
    const int KVD = NKVV * HDD;      // 512

    // workspace layout (bf16 buffers)
    char* ws = (char*)d_ws;
    size_t off = 0;
    auto alloc = [&](size_t elems) { __hip_bfloat16* p = (__hip_bfloat16*)(ws + off); off += elems * 2; return p; };
    __hip_bfloat16* xb  = alloc((size_t)M * DIMD);      // 16 MB
    __hip_bfloat16* wqb = alloc((size_t)DIMD * DIMD);   //  8 MB
    __hip_bfloat16* wkb = alloc((size_t)KVD * DIMD);    //  2 MB
    __hip_bfloat16* wvb = alloc((size_t)KVD * DIMD);    //  2 MB
    __hip_bfloat16* wob = alloc((size_t)DIMD * DIMD);   //  8 MB
    __hip_bfloat16* qbuf = alloc((size_t)M * DIMD);     // 16 MB
    __hip_bfloat16* kbuf = alloc((size_t)M * KVD);      //  4 MB
    __hip_bfloat16* vbuf = alloc((size_t)M * KVD);      //  4 MB
    __hip_bfloat16* abuf = alloc((size_t)M * DIMD);     // 16 MB

    // f32 -> bf16 conversions
    auto cvt = [&](const float* src, __hip_bfloat16* dst, size_t n) {
        cvt_f32_bf16<<<dim3((n / 4 + 255) / 256), 256, 0, stream>>>(src, dst, (int)n);
    };
    cvt(x,  xb,  (size_t)M * DIMD);
    cvt(Wq, wqb, (size_t)DIMD * DIMD);
    cvt(Wk, wkb, (size_t)KVD * DIMD);
    cvt(Wv, wvb, (size_t)KVD * DIMD);
    cvt(Wo, wob, (size_t)DIMD * DIMD);

    // QKV projections (bf16 out)
    gemm_bt<__hip_bfloat16><<<dim3(M / 128, DIMD / 128), 256, 0, stream>>>(xb, wqb, qbuf, M, DIMD, DIMD);
    gemm_bt<__hip_bfloat16><<<dim3(M / 128, KVD / 128), 256, 0, stream>>>(xb, wkb, kbuf, M, KVD, DIMD);
    gemm_bt<__hip_bfloat16><<<dim3(M / 128, KVD / 128), 256, 0, stream>>>(xb, wvb, vbuf, M, KVD, DIMD);

    // RoPE on q and k
    {
        int totq = M * NHH * 32;
        rope_kernel<<<(totq + 255) / 256, 256, 0, stream>>>(qbuf, rc, rs, NHH);
        int totk = M * NKVV * 32;
        rope_kernel<<<(totk + 255) / 256, 256, 0, stream>>>(kbuf, rc, rs, NKVV);
    }

    // attention (MFMA)
    attn_mfma<<<dim3(SEQ / 64, NHH, BB), 256, 0, stream>>>(qbuf, kbuf, vbuf, dc, abuf);

    // output projection (f32 out)
    gemm_bt<float><<<dim3(M / 128, DIMD / 128), 256, 0, stream>>>(abuf, wob, out, M, DIMD, DIMD);
}

// Round 4
// 505.744 us; speedup vs baseline: 3.7044x; 1.4747x over previous
//
#include <hip/hip_runtime.h>
#include <hip/hip_bf16.h>

// Problem constants
#define BB   2
#define SEQ  2048
#define DIMD 2048
#define NHH  32
#define NKVV 8
#define HDD  64
// N_REP = 4

typedef __bf16 bf16x8 __attribute__((ext_vector_type(8)));
typedef float  floatx4 __attribute__((ext_vector_type(4)));

typedef __attribute__((address_space(1))) const void* gas_ptr;
typedef __attribute__((address_space(3))) void*       las_ptr;

__device__ __forceinline__ unsigned short f2bu(float f) {
    __hip_bfloat16 h = __float2bfloat16(f);
    return *reinterpret_cast<unsigned short*>(&h);
}

// ---------------------------------------------------------------------------
// f32 -> bf16 conversion (vectorized by 4)
// ---------------------------------------------------------------------------
__global__ void cvt_f32_bf16(const float* __restrict__ in, __hip_bfloat16* __restrict__ out, int n) {
    int i = (blockIdx.x * blockDim.x + threadIdx.x) * 4;
    if (i >= n) return;
    float4 v = *reinterpret_cast<const float4*>(in + i);
    out[i + 0] = __float2bfloat16(v.x);
    out[i + 1] = __float2bfloat16(v.y);
    out[i + 2] = __float2bfloat16(v.z);
    out[i + 3] = __float2bfloat16(v.w);
}

// ---------------------------------------------------------------------------
// GEMM (m97-style): C[M,ldc] = A[M,K] @ W[N,K]^T, bf16 in, f32 acc.
// 128x128 block tile, BK=32, global_load_lds width=16 staging.
// LDS k-group XOR swizzle (slot = g ^ ((row>>1)&3)) -> 2-way-max bank aliasing
// on ds_read_b128 fragment reads (free per m136).
// ---------------------------------------------------------------------------
template <typename OutT>
__global__ __launch_bounds__(256) void gemm_lds(
    const __hip_bfloat16* __restrict__ Abf,
    const __hip_bfloat16* __restrict__ Wbf,
    OutT* __restrict__ C,
    int M, int N, int K, int ldc)
{
    const __bf16* A = reinterpret_cast<const __bf16*>(Abf);
    const __bf16* W = reinterpret_cast<const __bf16*>(Wbf);

    __shared__ __bf16 As[128 * 32];   // 8 KB
    __shared__ __bf16 Bs[128 * 32];   // 8 KB

    int tid  = threadIdx.x;
    int wid  = tid >> 6;
    int lane = tid & 63;
    int l15  = lane & 15;
    int l4   = lane >> 4;
    int wm   = (wid & 1) * 64;
    int wn   = (wid >> 1) * 64;
    int bm   = blockIdx.x * 128;
    int bn   = blockIdx.y * 128;

    // staging: 512 chunks of 16B per tile; thread handles chunks tid, tid+256.
    // chunk c -> LDS row r=c>>2, slot=c&3; fetches global k-group g = slot ^ ((r>>1)&3)
    int r0 = tid >> 2,         g0 = (tid & 3) ^ ((r0 >> 1) & 3);
    int r1 = (tid + 256) >> 2, g1 = (tid & 3) ^ ((r1 >> 1) & 3);

    const __bf16* a0 = A + (size_t)(bm + r0) * K + g0 * 8;
    const __bf16* a1 = A + (size_t)(bm + r1) * K + g1 * 8;
    const __bf16* w0 = W + (size_t)(bn + r0) * K + g0 * 8;
    const __bf16* w1 = W + (size_t)(bn + r1) * K + g1 * 8;

    __bf16* lA0 = As + tid * 8;
    __bf16* lA1 = As + (tid + 256) * 8;
    __bf16* lB0 = Bs + tid * 8;
    __bf16* lB1 = Bs + (tid + 256) * 8;

    // fragment read offsets (precomputed swizzled slots)
    int arow[4], aslot[4], brow[4], bslot[4];
    #pragma unroll
    for (int i = 0; i < 4; ++i) {
        int ra = wm + i * 16 + l15;
        int rb = wn + i * 16 + l15;
        arow[i] = ra; aslot[i] = l4 ^ ((ra >> 1) & 3);
        brow[i] = rb; bslot[i] = l4 ^ ((rb >> 1) & 3);
    }

    floatx4 acc[4][4] = {};

    for (int k0 = 0; k0 < K; k0 += 32) {
        __builtin_amdgcn_global_load_lds((gas_ptr)(a0 + k0), (las_ptr)lA0, 16, 0, 0);
        __builtin_amdgcn_global_load_lds((gas_ptr)(a1 + k0), (las_ptr)lA1, 16, 0, 0);
        __builtin_amdgcn_global_load_lds((gas_ptr)(w0 + k0), (las_ptr)lB0, 16, 0, 0);
        __builtin_amdgcn_global_load_lds((gas_ptr)(w1 + k0), (las_ptr)lB1, 16, 0, 0);
        __syncthreads();   // drains vmcnt + barrier

        bf16x8 af[4], bfr[4];
        #pragma unroll
        for (int i = 0; i < 4; ++i)
            af[i] = *reinterpret_cast<const bf16x8*>(As + arow[i] * 32 + aslot[i] * 8);
        #pragma unroll
        for (int j = 0; j < 4; ++j)
            bfr[j] = *reinterpret_cast<const bf16x8*>(Bs + brow[j] * 32 + bslot[j] * 8);

        #pragma unroll
        for (int i = 0; i < 4; ++i)
            #pragma unroll
            for (int j = 0; j < 4; ++j)
                acc[i][j] = __builtin_amdgcn_mfma_f32_16x16x32_bf16(af[i], bfr[j], acc[i][j], 0, 0, 0);
        __syncthreads();   // LDS reads done before restage
    }

    #pragma unroll
    for (int i = 0; i < 4; ++i)
        #pragma unroll
        for (int j = 0; j < 4; ++j)
            #pragma unroll
            for (int r = 0; r < 4; ++r) {
                int row = bm + wm + i * 16 + l4 * 4 + r;
                int col = bn + wn + j * 16 + l15;
                if constexpr (sizeof(OutT) == 4)
                    C[(size_t)row * ldc + col] = acc[i][j][r];
                else
                    C[(size_t)row * ldc + col] = __float2bfloat16(acc[i][j][r]);
            }
}

// ---------------------------------------------------------------------------
// RoPE (in-place, [B*S] rows, `heads` heads at row stride `stride`)
// pair (d, d+32); f32 cos/sin [s][d], d<32
// ---------------------------------------------------------------------------
__global__ void rope_kernel(__hip_bfloat16* buf,
                            const float* __restrict__ cosb,
                            const float* __restrict__ sinb,
                            int heads, int stride)
{
    int idx = blockIdx.x * blockDim.x + threadIdx.x;
    int total = (BB * SEQ) * heads * 32;
    if (idx >= total) return;
    int d   = idx & 31;
    int h   = (idx >> 5) % heads;
    int row = idx / (heads * 32);
    int s   = row & (SEQ - 1);
    size_t base = (size_t)row * stride + h * 64 + d;
    float x1 = __bfloat162float(buf[base]);
    float x2 = __bfloat162float(buf[base + 32]);
    float c  = cosb[s * 32 + d];
    float sn = sinb[s * 32 + d];
    buf[base]      = __float2bfloat16(x1 * c - x2 * sn);
    buf[base + 32] = __float2bfloat16(x2 * c + x1 * sn);
}

// ---------------------------------------------------------------------------
// MFMA flash attention with doc + causal mask.
// grid (S/64, NH, B), qblk reversed; block 256 (4 waves).
// q/k/v live in the fused qkv buffer (row stride QKVS).
// ---------------------------------------------------------------------------
#define QKVS 3072
__global__ __launch_bounds__(256) void attn_mfma(
    const __hip_bfloat16* __restrict__ qkv,  // [B*S][3072]: q | k | v
    const int* __restrict__ doc,             // [B][S]
    __hip_bfloat16* __restrict__ ob)         // [B*S][NH*64]
{
    int qblk = (int)gridDim.x - 1 - (int)blockIdx.x;   // heavy blocks first
    int h    = blockIdx.y;
    int b    = blockIdx.z;
    int kvh  = h >> 2;           // N_REP = 4
    int tid  = threadIdx.x;
    int wv   = tid >> 6;
    int lane = tid & 63;
    int l15  = lane & 15;
    int l4   = lane >> 4;
    int q0   = qblk * 64;
    int qw   = q0 + wv * 16;     // wave's query base

    __shared__ unsigned short Ks[64][72];   // [key][dim]
    __shared__ unsigned short Vt[64][72];   // [dim][key]
    __shared__ unsigned short Pb[4][16][72];// per-wave P tile [qrow][key]
    __shared__ int kdoc[64];

    const unsigned short* qus = reinterpret_cast<const unsigned short*>(qkv);
    const unsigned short* kus = qus + 2048;
    const unsigned short* vus = qus + 2560;

    bf16x8 aq[2];
    {
        const unsigned short* qrow = qus + (size_t)(b * SEQ + qw + l15) * QKVS + h * HDD;
        aq[0] = *reinterpret_cast<const bf16x8*>(qrow + l4 * 8);
        aq[1] = *reinterpret_cast<const bf16x8*>(qrow + 32 + l4 * 8);
    }
    int qd[4];
    #pragma unroll
    for (int r = 0; r < 4; ++r) qd[r] = doc[b * SEQ + qw + l4 * 4 + r];

    float mrow[4], lrow[4];
    #pragma unroll
    for (int r = 0; r < 4; ++r) { mrow[r] = -1e30f; lrow[r] = 0.f; }
    floatx4 accO[4] = {};

    int skey = tid >> 2;
    int scc  = tid & 3;

    for (int kc = 0; kc <= qblk; ++kc) {
        int k0 = kc * 64;
        __syncthreads();
        {
            const unsigned short* krow = kus + (size_t)(b * SEQ + k0 + skey) * QKVS + kvh * HDD;
            const unsigned short* vrow = vus + (size_t)(b * SEQ + k0 + skey) * QKVS + kvh * HDD;
            #pragma unroll
            for (int it = 0; it < 4; ++it) {
                int d0 = it * 16 + scc * 4;
                ushort4 ku = *reinterpret_cast<const ushort4*>(krow + d0);
                ushort4 vu = *reinterpret_cast<const ushort4*>(vrow + d0);
                *reinterpret_cast<ushort4*>(&Ks[skey][d0]) = ku;
                Vt[d0 + 0][skey] = vu.x;
                Vt[d0 + 1][skey] = vu.y;
                Vt[d0 + 2][skey] = vu.z;
                Vt[d0 + 3][skey] = vu.w;
            }
            if (tid < 64) kdoc[tid] = doc[b * SEQ + k0 + tid];
        }
        __syncthreads();

        // ---- QK^T ----
        float s[4][4];
        #pragma unroll
        for (int t = 0; t < 4; ++t) {
            bf16x8 bk0 = *reinterpret_cast<const bf16x8*>(&Ks[t * 16 + l15][l4 * 8]);
            bf16x8 bk1 = *reinterpret_cast<const bf16x8*>(&Ks[t * 16 + l15][32 + l4 * 8]);
            floatx4 acc = {};
            acc = __builtin_amdgcn_mfma_f32_16x16x32_bf16(aq[0], bk0, acc, 0, 0, 0);
            acc = __builtin_amdgcn_mfma_f32_16x16x32_bf16(aq[1], bk1, acc, 0, 0, 0);
            int key = k0 + t * 16 + l15;
            int kd  = kdoc[t * 16 + l15];
            #pragma unroll
            for (int r = 0; r < 4; ++r) {
                int qrow = qw + l4 * 4 + r;
                bool valid = (kd == qd[r]) && (key <= qrow);
                s[t][r] = valid ? acc[r] * 0.125f : -1e30f;
            }
        }

        // ---- online softmax ----
        float pval[4][4];
        #pragma unroll
        for (int r = 0; r < 4; ++r) {
            float pm = fmaxf(fmaxf(s[0][r], s[1][r]), fmaxf(s[2][r], s[3][r]));
            pm = fmaxf(pm, __shfl_xor(pm, 1));
            pm = fmaxf(pm, __shfl_xor(pm, 2));
            pm = fmaxf(pm, __shfl_xor(pm, 4));
            pm = fmaxf(pm, __shfl_xor(pm, 8));
            float mnew = fmaxf(mrow[r], pm);
            float alpha = __expf(mrow[r] - mnew);
            mrow[r] = mnew;
            float ps = 0.f;
            #pragma unroll
            for (int t = 0; t < 4; ++t) {
                float p = (s[t][r] <= -1e29f) ? 0.f : __expf(s[t][r] - mnew);
                pval[t][r] = p;
                ps += p;
            }
            ps += __shfl_xor(ps, 1);
            ps += __shfl_xor(ps, 2);
            ps += __shfl_xor(ps, 4);
            ps += __shfl_xor(ps, 8);
            lrow[r] = lrow[r] * alpha + ps;
            #pragma unroll
            for (int t = 0; t < 4; ++t) accO[t][r] *= alpha;
        }

        // ---- P: C layout -> LDS -> A layout ----
        #pragma unroll
        for (int t = 0; t < 4; ++t)
            #pragma unroll
            for (int r = 0; r < 4; ++r)
                Pb[wv][l4 * 4 + r][t * 16 + l15] = f2bu(pval[t][r]);
        __syncthreads();

        bf16x8 ap0 = *reinterpret_cast<const bf16x8*>(&Pb[wv][l15][l4 * 8]);
        bf16x8 ap1 = *reinterpret_cast<const bf16x8*>(&Pb[wv][l15][32 + l4 * 8]);

        // ---- PV ----
        #pragma unroll
        for (int t = 0; t < 4; ++t) {
            bf16x8 bv0 = *reinterpret_cast<const bf16x8*>(&Vt[t * 16 + l15][l4 * 8]);
            bf16x8 bv1 = *reinterpret_cast<const bf16x8*>(&Vt[t * 16 + l15][32 + l4 * 8]);
            accO[t] = __builtin_amdgcn_mfma_f32_16x16x32_bf16(ap0, bv0, accO[t], 0, 0, 0);
            accO[t] = __builtin_amdgcn_mfma_f32_16x16x32_bf16(ap1, bv1, accO[t], 0, 0, 0);
        }
    }

    #pragma unroll
    for (int r = 0; r < 4; ++r) {
        float inv = 1.0f / lrow[r];
        size_t base = (size_t)(b * SEQ + qw + l4 * 4 + r) * (NHH * HDD) + h * HDD;
        #pragma unroll
        for (int t = 0; t < 4; ++t)
            ob[base + t * 16 + l15] = __float2bfloat16(accO[t][r] * inv);
    }
}

// ---------------------------------------------------------------------------
extern "C" void kernel_launch(void* const* d_in, const int* in_sizes, int n_in,
                              void* d_out, int out_size, void* d_ws, size_t ws_size,
                              hipStream_t stream) {
    const float* x  = (const float*)d_in[0];
    const float* rc = (const float*)d_in[1];
    const float* rs = (const float*)d_in[2];
    const int*   dc = (const int*)d_in[3];
    const float* Wq = (const float*)d_in[4];
    const float* Wk = (const float*)d_in[5];
    const float* Wv = (const float*)d_in[6];
    const float* Wo = (const float*)d_in[7];
    float* out = (float*)d_out;

    const int M   = BB * SEQ;        // 4096
    const int KVD = NKVV * HDD;      // 512
    const int QKVN = DIMD + 2 * KVD; // 3072

    // workspace layout (bf16 buffers)
    char* ws = (char*)d_ws;
    size_t off = 0;
    auto alloc = [&](size_t elems) { __hip_bfloat16* p = (__hip_bfloat16*)(ws + off); off += elems * 2; return p; };
    __hip_bfloat16* xb   = alloc((size_t)M * DIMD);      // 16 MB
    __hip_bfloat16* wqkv = alloc((size_t)QKVN * DIMD);   // 12 MB  (Wq|Wk|Wv rows)
    __hip_bfloat16* wob  = alloc((size_t)DIMD * DIMD);   //  8 MB
    __hip_bfloat16* qkv  = alloc((size_t)M * QKVN);      // 24 MB
    __hip_bfloat16* abuf = alloc((size_t)M * DIMD);      // 16 MB

    // f32 -> bf16 conversions
    auto cvt = [&](const float* src, __hip_bfloat16* dst, size_t n) {
        cvt_f32_bf16<<<dim3((n / 4 + 255) / 256), 256, 0, stream>>>(src, dst, (int)n);
    };
    cvt(x,  xb,   (size_t)M * DIMD);
    cvt(Wq, wqkv,                          (size_t)DIMD * DIMD);
    cvt(Wk, wqkv + (size_t)DIMD * DIMD,    (size_t)KVD * DIMD);
    cvt(Wv, wqkv + (size_t)(DIMD + KVD) * DIMD, (size_t)KVD * DIMD);
    cvt(Wo, wob,  (size_t)DIMD * DIMD);

    // fused QKV projection: [4096][3072]
    gemm_lds<__hip_bfloat16><<<dim3(M / 128, QKVN / 128), 256, 0, stream>>>(
        xb, wqkv, qkv, M, QKVN, DIMD, QKVN);

    // RoPE on q (cols 0..2047, 32 heads) and k (cols 2048..2559, 8 heads)
    {
        int totq = M * NHH * 32;
        rope_kernel<<<(totq + 255) / 256, 256, 0, stream>>>(qkv, rc, rs, NHH, QKVN);
        int totk = M * NKVV * 32;
        rope_kernel<<<(totk + 255) / 256, 256, 0, stream>>>(qkv + DIMD, rc, rs, NKVV, QKVN);
    }

    // attention (MFMA)
    attn_mfma<<<dim3(SEQ / 64, NHH, BB), 256, 0, stream>>>(qkv, dc, abuf);

    // output projection (f32 out)
    gemm_lds<float><<<dim3(M / 128, DIMD / 128), 256, 0, stream>>>(
        abuf, wob, out, M, DIMD, DIMD, DIMD);
}

// Round 5
// 315.317 us; speedup vs baseline: 5.9416x; 1.6039x over previous
//
#include <hip/hip_runtime.h>
#include <hip/hip_bf16.h>

// Problem constants
#define BB   2
#define SEQ  2048
#define DIMD 2048
#define NHH  32
#define NKVV 8
#define HDD  64
#define QKVS 3072
// N_REP = 4

typedef __bf16 bf16x8 __attribute__((ext_vector_type(8)));
typedef float  floatx4 __attribute__((ext_vector_type(4)));

typedef __attribute__((address_space(1))) const void* gas_ptr;
typedef __attribute__((address_space(3))) void*       las_ptr;

__device__ __forceinline__ unsigned short f2bu(float f) {
    __hip_bfloat16 h = __float2bfloat16(f);
    return *reinterpret_cast<unsigned short*>(&h);
}

// ---------------------------------------------------------------------------
// f32 -> bf16 conversion (vectorized by 4)
// ---------------------------------------------------------------------------
__global__ void cvt_f32_bf16(const float* __restrict__ in, __hip_bfloat16* __restrict__ out, int n) {
    int i = (blockIdx.x * blockDim.x + threadIdx.x) * 4;
    if (i >= n) return;
    float4 v = *reinterpret_cast<const float4*>(in + i);
    out[i + 0] = __float2bfloat16(v.x);
    out[i + 1] = __float2bfloat16(v.y);
    out[i + 2] = __float2bfloat16(v.z);
    out[i + 3] = __float2bfloat16(v.w);
}

// ---------------------------------------------------------------------------
// GEMM (m97-style): C[M,ldc] = A[M,K] @ W[N,K]^T, bf16 in, f32 acc.
// ---------------------------------------------------------------------------
template <typename OutT>
__global__ __launch_bounds__(256) void gemm_lds(
    const __hip_bfloat16* __restrict__ Abf,
    const __hip_bfloat16* __restrict__ Wbf,
    OutT* __restrict__ C,
    int M, int N, int K, int ldc)
{
    const __bf16* A = reinterpret_cast<const __bf16*>(Abf);
    const __bf16* W = reinterpret_cast<const __bf16*>(Wbf);

    __shared__ __bf16 As[128 * 32];   // 8 KB
    __shared__ __bf16 Bs[128 * 32];   // 8 KB

    int tid  = threadIdx.x;
    int wid  = tid >> 6;
    int lane = tid & 63;
    int l15  = lane & 15;
    int l4   = lane >> 4;
    int wm   = (wid & 1) * 64;
    int wn   = (wid >> 1) * 64;
    int bm   = blockIdx.x * 128;
    int bn   = blockIdx.y * 128;

    int r0 = tid >> 2,         g0 = (tid & 3) ^ ((r0 >> 1) & 3);
    int r1 = (tid + 256) >> 2, g1 = (tid & 3) ^ ((r1 >> 1) & 3);

    const __bf16* a0 = A + (size_t)(bm + r0) * K + g0 * 8;
    const __bf16* a1 = A + (size_t)(bm + r1) * K + g1 * 8;
    const __bf16* w0 = W + (size_t)(bn + r0) * K + g0 * 8;
    const __bf16* w1 = W + (size_t)(bn + r1) * K + g1 * 8;

    __bf16* lA0 = As + tid * 8;
    __bf16* lA1 = As + (tid + 256) * 8;
    __bf16* lB0 = Bs + tid * 8;
    __bf16* lB1 = Bs + (tid + 256) * 8;

    int arow[4], aslot[4], brow[4], bslot[4];
    #pragma unroll
    for (int i = 0; i < 4; ++i) {
        int ra = wm + i * 16 + l15;
        int rb = wn + i * 16 + l15;
        arow[i] = ra; aslot[i] = l4 ^ ((ra >> 1) & 3);
        brow[i] = rb; bslot[i] = l4 ^ ((rb >> 1) & 3);
    }

    floatx4 acc[4][4] = {};

    for (int k0 = 0; k0 < K; k0 += 32) {
        __builtin_amdgcn_global_load_lds((gas_ptr)(a0 + k0), (las_ptr)lA0, 16, 0, 0);
        __builtin_amdgcn_global_load_lds((gas_ptr)(a1 + k0), (las_ptr)lA1, 16, 0, 0);
        __builtin_amdgcn_global_load_lds((gas_ptr)(w0 + k0), (las_ptr)lB0, 16, 0, 0);
        __builtin_amdgcn_global_load_lds((gas_ptr)(w1 + k0), (las_ptr)lB1, 16, 0, 0);
        __syncthreads();

        bf16x8 af[4], bfr[4];
        #pragma unroll
        for (int i = 0; i < 4; ++i)
            af[i] = *reinterpret_cast<const bf16x8*>(As + arow[i] * 32 + aslot[i] * 8);
        #pragma unroll
        for (int j = 0; j < 4; ++j)
            bfr[j] = *reinterpret_cast<const bf16x8*>(Bs + brow[j] * 32 + bslot[j] * 8);

        #pragma unroll
        for (int i = 0; i < 4; ++i)
            #pragma unroll
            for (int j = 0; j < 4; ++j)
                acc[i][j] = __builtin_amdgcn_mfma_f32_16x16x32_bf16(af[i], bfr[j], acc[i][j], 0, 0, 0);
        __syncthreads();
    }

    #pragma unroll
    for (int i = 0; i < 4; ++i)
        #pragma unroll
        for (int j = 0; j < 4; ++j)
            #pragma unroll
            for (int r = 0; r < 4; ++r) {
                int row = bm + wm + i * 16 + l4 * 4 + r;
                int col = bn + wn + j * 16 + l15;
                if constexpr (sizeof(OutT) == 4)
                    C[(size_t)row * ldc + col] = acc[i][j][r];
                else
                    C[(size_t)row * ldc + col] = __float2bfloat16(acc[i][j][r]);
            }
}

// ---------------------------------------------------------------------------
// RoPE (in-place, [B*S] rows, `heads` heads at row stride `stride`)
// ---------------------------------------------------------------------------
__global__ void rope_kernel(__hip_bfloat16* buf,
                            const float* __restrict__ cosb,
                            const float* __restrict__ sinb,
                            int heads, int stride)
{
    int idx = blockIdx.x * blockDim.x + threadIdx.x;
    int total = (BB * SEQ) * heads * 32;
    if (idx >= total) return;
    int d   = idx & 31;
    int h   = (idx >> 5) % heads;
    int row = idx / (heads * 32);
    int s   = row & (SEQ - 1);
    size_t base = (size_t)row * stride + h * 64 + d;
    float x1 = __bfloat162float(buf[base]);
    float x2 = __bfloat162float(buf[base + 32]);
    float c  = cosb[s * 32 + d];
    float sn = sinb[s * 32 + d];
    buf[base]      = __float2bfloat16(x1 * c - x2 * sn);
    buf[base + 32] = __float2bfloat16(x2 * c + x1 * sn);
}

// ---------------------------------------------------------------------------
// V transpose: vT[b][kvh][d][s] <- qkv v-section [b*S+s][2560 + kvh*64 + d]
// grid (S/64, NKV, B), block 256
// ---------------------------------------------------------------------------
__global__ void transpose_v(const __hip_bfloat16* __restrict__ qkv,
                            unsigned short* __restrict__ vT)
{
    __shared__ unsigned short T[64][68];
    int s0  = blockIdx.x * 64;
    int kvh = blockIdx.y;
    int b   = blockIdx.z;
    int tid = threadIdx.x;

    int srow = tid >> 2, dg = (tid & 3) * 16;
    const unsigned short* src = reinterpret_cast<const unsigned short*>(qkv)
        + (size_t)(b * SEQ + s0 + srow) * QKVS + 2560 + kvh * 64 + dg;
    #pragma unroll
    for (int i = 0; i < 4; ++i)
        *reinterpret_cast<ushort4*>(&T[srow][dg + i * 4]) =
            *reinterpret_cast<const ushort4*>(src + i * 4);
    __syncthreads();

    int drow = tid >> 2, sg = (tid & 3) * 16;
    unsigned short* dst = vT + ((size_t)(b * NKVV + kvh) * 64 + drow) * SEQ + s0 + sg;
    #pragma unroll
    for (int i = 0; i < 4; ++i) {
        ushort4 u;
        u.x = T[sg + i * 4 + 0][drow];
        u.y = T[sg + i * 4 + 1][drow];
        u.z = T[sg + i * 4 + 2][drow];
        u.w = T[sg + i * 4 + 3][drow];
        *reinterpret_cast<ushort4*>(dst + i * 4) = u;
    }
}

// ---------------------------------------------------------------------------
// MFMA flash attention, doc+causal, doc-skip at chunk level.
// grid (S/128, NH, B) reversed; block 256 (4 waves), wave owns 32 queries.
// K and V^T tiles (64x64 bf16, unpadded) staged via global_load_lds with
// XOR chunk swizzle slot = g ^ (row&7); frag reads land 2-way max (free).
// ---------------------------------------------------------------------------
__global__ __launch_bounds__(256) void attn_mfma(
    const __hip_bfloat16* __restrict__ qkv,  // [B*S][3072]: q | k | v
    const unsigned short* __restrict__ vT,   // [B][NKV][64][S]
    const int* __restrict__ doc,             // [B][S]
    __hip_bfloat16* __restrict__ ob)         // [B*S][NH*64]
{
    int qblk = (int)gridDim.x - 1 - (int)blockIdx.x;   // heavy blocks first
    int h    = blockIdx.y;
    int b    = blockIdx.z;
    int kvh  = h >> 2;
    int tid  = threadIdx.x;
    int wv   = tid >> 6;
    int lane = tid & 63;
    int l15  = lane & 15;
    int l4   = lane >> 4;
    int q0   = qblk * 128;
    int qw   = q0 + wv * 32;

    __shared__ unsigned short Ks[64 * 64];    // [key][dim], swizzled chunks
    __shared__ unsigned short Vts[64 * 64];   // [dim][key], swizzled chunks
    __shared__ unsigned short Pb[4][32][76];  // per-wave P tile
    __shared__ int kdoc[64];

    const unsigned short* qus = reinterpret_cast<const unsigned short*>(qkv);
    const unsigned short* kus = qus + 2048;

    // Q fragments: 2 tiles of 16 rows
    bf16x8 aq[2][2];
    #pragma unroll
    for (int qt = 0; qt < 2; ++qt) {
        const unsigned short* qrow = qus + (size_t)(b * SEQ + qw + qt * 16 + l15) * QKVS + h * HDD;
        aq[qt][0] = *reinterpret_cast<const bf16x8*>(qrow + l4 * 8);
        aq[qt][1] = *reinterpret_cast<const bf16x8*>(qrow + 32 + l4 * 8);
    }
    int qd[2][4];
    #pragma unroll
    for (int qt = 0; qt < 2; ++qt)
        #pragma unroll
        for (int r = 0; r < 4; ++r)
            qd[qt][r] = doc[b * SEQ + qw + qt * 16 + l4 * 4 + r];
    int qd_w   = doc[b * SEQ + qw];   // sorted -> wave min
    int qd_blk = doc[b * SEQ + q0];   // block min

    float mrow[2][4], lrow[2][4];
    #pragma unroll
    for (int qt = 0; qt < 2; ++qt)
        #pragma unroll
        for (int r = 0; r < 4; ++r) { mrow[qt][r] = -1e30f; lrow[qt][r] = 0.f; }
    floatx4 accO[2][4] = {};

    // staging slot mapping: slot -> (row = slot>>3, s = slot&7), global chunk g = s ^ (row&7)
    int slot0 = tid, slot1 = tid + 256;
    int row0 = slot0 >> 3, g0 = (slot0 & 7) ^ (row0 & 7);
    int row1 = slot1 >> 3, g1 = (slot1 & 7) ^ (row1 & 7);
    const unsigned short* vtb = vT + ((size_t)(b * NKVV + kvh) * 64) * SEQ;

    int kc_end = 2 * qblk + 1;
    for (int kc = 0; kc <= kc_end; ++kc) {
        int k0 = kc * 64;
        int kd_last = doc[b * SEQ + k0 + 63];
        if (kd_last < qd_blk) continue;        // block-uniform doc skip

        __syncthreads();   // previous chunk's LDS reads done
        __builtin_amdgcn_global_load_lds(
            (gas_ptr)(kus + (size_t)(b * SEQ + k0 + row0) * QKVS + kvh * HDD + g0 * 8),
            (las_ptr)(Ks + slot0 * 8), 16, 0, 0);
        __builtin_amdgcn_global_load_lds(
            (gas_ptr)(kus + (size_t)(b * SEQ + k0 + row1) * QKVS + kvh * HDD + g1 * 8),
            (las_ptr)(Ks + slot1 * 8), 16, 0, 0);
        __builtin_amdgcn_global_load_lds(
            (gas_ptr)(vtb + (size_t)row0 * SEQ + k0 + g0 * 8),
            (las_ptr)(Vts + slot0 * 8), 16, 0, 0);
        __builtin_amdgcn_global_load_lds(
            (gas_ptr)(vtb + (size_t)row1 * SEQ + k0 + g1 * 8),
            (las_ptr)(Vts + slot1 * 8), 16, 0, 0);
        if (tid < 64) kdoc[tid] = doc[b * SEQ + k0 + tid];
        __syncthreads();   // staged (vmcnt drained by barrier)

        if (k0 <= qw + 31 && kd_last >= qd_w) {   // wave-uniform compute skip
            #pragma unroll
            for (int qt = 0; qt < 2; ++qt) {
                // ---- QK^T: 4 key tiles ----
                float s[4][4];
                #pragma unroll
                for (int t = 0; t < 4; ++t) {
                    int krow = t * 16 + l15;
                    bf16x8 bk0 = *reinterpret_cast<const bf16x8*>(Ks + krow * 64 + ((l4 ^ (krow & 7)) * 8));
                    bf16x8 bk1 = *reinterpret_cast<const bf16x8*>(Ks + krow * 64 + ((((l4 + 4)) ^ (krow & 7)) * 8));
                    floatx4 acc = {};
                    acc = __builtin_amdgcn_mfma_f32_16x16x32_bf16(aq[qt][0], bk0, acc, 0, 0, 0);
                    acc = __builtin_amdgcn_mfma_f32_16x16x32_bf16(aq[qt][1], bk1, acc, 0, 0, 0);
                    int key = k0 + krow;
                    int kd  = kdoc[krow];
                    #pragma unroll
                    for (int r = 0; r < 4; ++r) {
                        int qrow = qw + qt * 16 + l4 * 4 + r;
                        bool valid = (kd == qd[qt][r]) && (key <= qrow);
                        s[t][r] = valid ? acc[r] * 0.125f : -1e30f;
                    }
                }
                // ---- online softmax ----
                #pragma unroll
                for (int r = 0; r < 4; ++r) {
                    float pm = fmaxf(fmaxf(s[0][r], s[1][r]), fmaxf(s[2][r], s[3][r]));
                    pm = fmaxf(pm, __shfl_xor(pm, 1));
                    pm = fmaxf(pm, __shfl_xor(pm, 2));
                    pm = fmaxf(pm, __shfl_xor(pm, 4));
                    pm = fmaxf(pm, __shfl_xor(pm, 8));
                    float mnew = fmaxf(mrow[qt][r], pm);
                    float alpha = __expf(mrow[qt][r] - mnew);
                    mrow[qt][r] = mnew;
                    float ps = 0.f;
                    #pragma unroll
                    for (int t = 0; t < 4; ++t) {
                        float p = (s[t][r] <= -1e29f) ? 0.f : __expf(s[t][r] - mnew);
                        Pb[wv][qt * 16 + l4 * 4 + r][t * 16 + l15] = f2bu(p);
                        ps += p;
                    }
                    ps += __shfl_xor(ps, 1);
                    ps += __shfl_xor(ps, 2);
                    ps += __shfl_xor(ps, 4);
                    ps += __shfl_xor(ps, 8);
                    lrow[qt][r] = lrow[qt][r] * alpha + ps;
                    #pragma unroll
                    for (int t = 0; t < 4; ++t) accO[qt][t][r] *= alpha;
                }
            }
            // ---- PV (P via wave-local LDS round-trip, no barrier) ----
            #pragma unroll
            for (int qt = 0; qt < 2; ++qt) {
                bf16x8 ap0 = *reinterpret_cast<const bf16x8*>(&Pb[wv][qt * 16 + l15][l4 * 8]);
                bf16x8 ap1 = *reinterpret_cast<const bf16x8*>(&Pb[wv][qt * 16 + l15][32 + l4 * 8]);
                #pragma unroll
                for (int t = 0; t < 4; ++t) {
                    int vrow = t * 16 + l15;
                    bf16x8 bv0 = *reinterpret_cast<const bf16x8*>(Vts + vrow * 64 + ((l4 ^ (vrow & 7)) * 8));
                    bf16x8 bv1 = *reinterpret_cast<const bf16x8*>(Vts + vrow * 64 + ((((l4 + 4)) ^ (vrow & 7)) * 8));
                    accO[qt][t] = __builtin_amdgcn_mfma_f32_16x16x32_bf16(ap0, bv0, accO[qt][t], 0, 0, 0);
                    accO[qt][t] = __builtin_amdgcn_mfma_f32_16x16x32_bf16(ap1, bv1, accO[qt][t], 0, 0, 0);
                }
            }
        }
    }

    #pragma unroll
    for (int qt = 0; qt < 2; ++qt)
        #pragma unroll
        for (int r = 0; r < 4; ++r) {
            float inv = 1.0f / lrow[qt][r];
            size_t base = (size_t)(b * SEQ + qw + qt * 16 + l4 * 4 + r) * (NHH * HDD) + h * HDD;
            #pragma unroll
            for (int t = 0; t < 4; ++t)
                ob[base + t * 16 + l15] = __float2bfloat16(accO[qt][t][r] * inv);
        }
}

// ---------------------------------------------------------------------------
extern "C" void kernel_launch(void* const* d_in, const int* in_sizes, int n_in,
                              void* d_out, int out_size, void* d_ws, size_t ws_size,
                              hipStream_t stream) {
    const float* x  = (const float*)d_in[0];
    const float* rc = (const float*)d_in[1];
    const float* rs = (const float*)d_in[2];
    const int*   dc = (const int*)d_in[3];
    const float* Wq = (const float*)d_in[4];
    const float* Wk = (const float*)d_in[5];
    const float* Wv = (const float*)d_in[6];
    const float* Wo = (const float*)d_in[7];
    float* out = (float*)d_out;

    const int M   = BB * SEQ;        // 4096
    const int KVD = NKVV * HDD;      // 512
    const int QKVN = DIMD + 2 * KVD; // 3072

    char* ws = (char*)d_ws;
    size_t off = 0;
    auto alloc = [&](size_t elems) { __hip_bfloat16* p = (__hip_bfloat16*)(ws + off); off += elems * 2; return p; };
    __hip_bfloat16* xb   = alloc((size_t)M * DIMD);      // 16 MB
    __hip_bfloat16* wqkv = alloc((size_t)QKVN * DIMD);   // 12 MB
    __hip_bfloat16* wob  = alloc((size_t)DIMD * DIMD);   //  8 MB
    __hip_bfloat16* qkv  = alloc((size_t)M * QKVN);      // 24 MB
    __hip_bfloat16* abuf = alloc((size_t)M * DIMD);      // 16 MB
    unsigned short* vtb  = (unsigned short*)alloc((size_t)BB * NKVV * HDD * SEQ); // 4 MB

    auto cvt = [&](const float* src, __hip_bfloat16* dst, size_t n) {
        cvt_f32_bf16<<<dim3((n / 4 + 255) / 256), 256, 0, stream>>>(src, dst, (int)n);
    };
    cvt(x,  xb,   (size_t)M * DIMD);
    cvt(Wq, wqkv,                               (size_t)DIMD * DIMD);
    cvt(Wk, wqkv + (size_t)DIMD * DIMD,         (size_t)KVD * DIMD);
    cvt(Wv, wqkv + (size_t)(DIMD + KVD) * DIMD, (size_t)KVD * DIMD);
    cvt(Wo, wob,  (size_t)DIMD * DIMD);

    // fused QKV projection: [4096][3072]
    gemm_lds<__hip_bfloat16><<<dim3(M / 128, QKVN / 128), 256, 0, stream>>>(
        xb, wqkv, qkv, M, QKVN, DIMD, QKVN);

    // RoPE on q and k sections
    {
        int totq = M * NHH * 32;
        rope_kernel<<<(totq + 255) / 256, 256, 0, stream>>>(qkv, rc, rs, NHH, QKVN);
        int totk = M * NKVV * 32;
        rope_kernel<<<(totk + 255) / 256, 256, 0, stream>>>(qkv + DIMD, rc, rs, NKVV, QKVN);
    }

    // V transpose for PV B-fragments
    transpose_v<<<dim3(SEQ / 64, NKVV, BB), 256, 0, stream>>>(qkv, vtb);

    // attention (MFMA, doc-skip)
    attn_mfma<<<dim3(SEQ / 128, NHH, BB), 256, 0, stream>>>(qkv, vtb, dc, abuf);

    // output projection (f32 out)
    gemm_lds<float><<<dim3(M / 128, DIMD / 128), 256, 0, stream>>>(
        abuf, wob, out, M, DIMD, DIMD, DIMD);
}

// Round 6
// 301.104 us; speedup vs baseline: 6.2220x; 1.0472x over previous
//
#include <hip/hip_runtime.h>
#include <hip/hip_bf16.h>

// Problem constants
#define BB   2
#define SEQ  2048
#define DIMD 2048
#define NHH  32
#define NKVV 8
#define HDD  64
#define QKVS 3072
// N_REP = 4

typedef __bf16 bf16x8 __attribute__((ext_vector_type(8)));
typedef float  floatx4 __attribute__((ext_vector_type(4)));

typedef __attribute__((address_space(1))) const void* gas_ptr;
typedef __attribute__((address_space(3))) void*       las_ptr;

__device__ __forceinline__ unsigned short f2bu(float f) {
    __hip_bfloat16 h = __float2bfloat16(f);
    return *reinterpret_cast<unsigned short*>(&h);
}

// ---------------------------------------------------------------------------
// Fused f32 -> bf16 conversion for all 5 inputs (one launch).
// Segments (in 4-elem units): x 2M | Wq 1M | Wk 256K | Wv 256K | Wo 1M
// ---------------------------------------------------------------------------
#define C_X  (8u  * 1024 * 1024)
#define C_WQ (4u  * 1024 * 1024)
#define C_WK (1u  * 1024 * 1024)
#define C_WV (1u  * 1024 * 1024)
#define C_WO (4u  * 1024 * 1024)
__global__ void cvt_all(const float* __restrict__ x,  const float* __restrict__ wq,
                        const float* __restrict__ wk, const float* __restrict__ wv,
                        const float* __restrict__ wo,
                        __hip_bfloat16* __restrict__ xb,
                        __hip_bfloat16* __restrict__ wqkv,
                        __hip_bfloat16* __restrict__ wob)
{
    unsigned i = (blockIdx.x * blockDim.x + threadIdx.x) * 4;
    const float* src; __hip_bfloat16* dst;
    if (i < C_X)                       { src = x  + i;                    dst = xb + i; }
    else if (i < C_X + C_WQ)           { unsigned o = i - C_X;            src = wq + o; dst = wqkv + o; }
    else if (i < C_X + C_WQ + C_WK)    { unsigned o = i - C_X - C_WQ;     src = wk + o; dst = wqkv + C_WQ + o; }
    else if (i < C_X + C_WQ + C_WK + C_WV) { unsigned o = i - C_X - C_WQ - C_WK; src = wv + o; dst = wqkv + C_WQ + C_WK + o; }
    else                               { unsigned o = i - C_X - C_WQ - C_WK - C_WV; if (o >= C_WO) return; src = wo + o; dst = wob + o; }
    float4 v = *reinterpret_cast<const float4*>(src);
    dst[0] = __float2bfloat16(v.x);
    dst[1] = __float2bfloat16(v.y);
    dst[2] = __float2bfloat16(v.z);
    dst[3] = __float2bfloat16(v.w);
}

// ---------------------------------------------------------------------------
// GEMM (m97-style): C[M,ldc] = A[M,K] @ W[N,K]^T, bf16 in, f32 acc.
// ROPE=true: apply RoPE in the f32 epilogue for cols < 2560 (q|k sections).
// Wave spans one 64-col head; pairs are acc[i][j] <-> acc[i][j+2], d=j*16+l15.
// ---------------------------------------------------------------------------
template <typename OutT, bool ROPE>
__global__ __launch_bounds__(256) void gemm_lds(
    const __hip_bfloat16* __restrict__ Abf,
    const __hip_bfloat16* __restrict__ Wbf,
    OutT* __restrict__ C,
    int M, int N, int K, int ldc,
    const float* __restrict__ cosb, const float* __restrict__ sinb)
{
    const __bf16* A = reinterpret_cast<const __bf16*>(Abf);
    const __bf16* W = reinterpret_cast<const __bf16*>(Wbf);

    __shared__ __bf16 As[128 * 32];   // 8 KB
    __shared__ __bf16 Bs[128 * 32];   // 8 KB

    int tid  = threadIdx.x;
    int wid  = tid >> 6;
    int lane = tid & 63;
    int l15  = lane & 15;
    int l4   = lane >> 4;
    int wm   = (wid & 1) * 64;
    int wn   = (wid >> 1) * 64;
    int bm   = blockIdx.x * 128;
    int bn   = blockIdx.y * 128;

    int r0 = tid >> 2,         g0 = (tid & 3) ^ ((r0 >> 1) & 3);
    int r1 = (tid + 256) >> 2, g1 = (tid & 3) ^ ((r1 >> 1) & 3);

    const __bf16* a0 = A + (size_t)(bm + r0) * K + g0 * 8;
    const __bf16* a1 = A + (size_t)(bm + r1) * K + g1 * 8;
    const __bf16* w0 = W + (size_t)(bn + r0) * K + g0 * 8;
    const __bf16* w1 = W + (size_t)(bn + r1) * K + g1 * 8;

    __bf16* lA0 = As + tid * 8;
    __bf16* lA1 = As + (tid + 256) * 8;
    __bf16* lB0 = Bs + tid * 8;
    __bf16* lB1 = Bs + (tid + 256) * 8;

    int arow[4], aslot[4], brow[4], bslot[4];
    #pragma unroll
    for (int i = 0; i < 4; ++i) {
        int ra = wm + i * 16 + l15;
        int rb = wn + i * 16 + l15;
        arow[i] = ra; aslot[i] = l4 ^ ((ra >> 1) & 3);
        brow[i] = rb; bslot[i] = l4 ^ ((rb >> 1) & 3);
    }

    floatx4 acc[4][4] = {};

    for (int k0 = 0; k0 < K; k0 += 32) {
        __builtin_amdgcn_global_load_lds((gas_ptr)(a0 + k0), (las_ptr)lA0, 16, 0, 0);
        __builtin_amdgcn_global_load_lds((gas_ptr)(a1 + k0), (las_ptr)lA1, 16, 0, 0);
        __builtin_amdgcn_global_load_lds((gas_ptr)(w0 + k0), (las_ptr)lB0, 16, 0, 0);
        __builtin_amdgcn_global_load_lds((gas_ptr)(w1 + k0), (las_ptr)lB1, 16, 0, 0);
        __syncthreads();

        bf16x8 af[4], bfr[4];
        #pragma unroll
        for (int i = 0; i < 4; ++i)
            af[i] = *reinterpret_cast<const bf16x8*>(As + arow[i] * 32 + aslot[i] * 8);
        #pragma unroll
        for (int j = 0; j < 4; ++j)
            bfr[j] = *reinterpret_cast<const bf16x8*>(Bs + brow[j] * 32 + bslot[j] * 8);

        #pragma unroll
        for (int i = 0; i < 4; ++i)
            #pragma unroll
            for (int j = 0; j < 4; ++j)
                acc[i][j] = __builtin_amdgcn_mfma_f32_16x16x32_bf16(af[i], bfr[j], acc[i][j], 0, 0, 0);
        __syncthreads();
    }

    if constexpr (ROPE) {
        bool do_rope = (bn + wn) < 2560;   // q|k sections; wave-uniform
        #pragma unroll
        for (int i = 0; i < 4; ++i) {
            #pragma unroll
            for (int r = 0; r < 4; ++r) {
                int row = bm + wm + i * 16 + l4 * 4 + r;
                int s   = row & (SEQ - 1);
                #pragma unroll
                for (int j = 0; j < 2; ++j) {
                    float x1 = acc[i][j][r], x2 = acc[i][j + 2][r];
                    if (do_rope) {
                        float cf = cosb[s * 32 + j * 16 + l15];
                        float sf = sinb[s * 32 + j * 16 + l15];
                        float o1 = x1 * cf - x2 * sf;
                        float o2 = x2 * cf + x1 * sf;
                        x1 = o1; x2 = o2;
                    }
                    int col = bn + wn + j * 16 + l15;
                    C[(size_t)row * ldc + col]      = __float2bfloat16(x1);
                    C[(size_t)row * ldc + col + 32] = __float2bfloat16(x2);
                }
            }
        }
    } else {
        #pragma unroll
        for (int i = 0; i < 4; ++i)
            #pragma unroll
            for (int j = 0; j < 4; ++j)
                #pragma unroll
                for (int r = 0; r < 4; ++r) {
                    int row = bm + wm + i * 16 + l4 * 4 + r;
                    int col = bn + wn + j * 16 + l15;
                    if constexpr (sizeof(OutT) == 4)
                        C[(size_t)row * ldc + col] = acc[i][j][r];
                    else
                        C[(size_t)row * ldc + col] = __float2bfloat16(acc[i][j][r]);
                }
    }
}

// ---------------------------------------------------------------------------
// V transpose: vT[b][kvh][d][s] <- qkv v-section [b*S+s][2560 + kvh*64 + d]
// ---------------------------------------------------------------------------
__global__ void transpose_v(const __hip_bfloat16* __restrict__ qkv,
                            unsigned short* __restrict__ vT)
{
    __shared__ unsigned short T[64][68];
    int s0  = blockIdx.x * 64;
    int kvh = blockIdx.y;
    int b   = blockIdx.z;
    int tid = threadIdx.x;

    int srow = tid >> 2, dg = (tid & 3) * 16;
    const unsigned short* src = reinterpret_cast<const unsigned short*>(qkv)
        + (size_t)(b * SEQ + s0 + srow) * QKVS + 2560 + kvh * 64 + dg;
    #pragma unroll
    for (int i = 0; i < 4; ++i)
        *reinterpret_cast<ushort4*>(&T[srow][dg + i * 4]) =
            *reinterpret_cast<const ushort4*>(src + i * 4);
    __syncthreads();

    int drow = tid >> 2, sg = (tid & 3) * 16;
    unsigned short* dst = vT + ((size_t)(b * NKVV + kvh) * 64 + drow) * SEQ + s0 + sg;
    #pragma unroll
    for (int i = 0; i < 4; ++i) {
        ushort4 u;
        u.x = T[sg + i * 4 + 0][drow];
        u.y = T[sg + i * 4 + 1][drow];
        u.z = T[sg + i * 4 + 2][drow];
        u.w = T[sg + i * 4 + 3][drow];
        *reinterpret_cast<ushort4*>(dst + i * 4) = u;
    }
}

// ---------------------------------------------------------------------------
// MFMA flash attention, doc+causal, doc-skip at chunk level.
// grid (S/128, NH, B) reversed; block 256 (4 waves), wave owns 32 queries.
// ---------------------------------------------------------------------------
__global__ __launch_bounds__(256) void attn_mfma(
    const __hip_bfloat16* __restrict__ qkv,  // [B*S][3072]: q | k | v
    const unsigned short* __restrict__ vT,   // [B][NKV][64][S]
    const int* __restrict__ doc,             // [B][S]
    __hip_bfloat16* __restrict__ ob)         // [B*S][NH*64]
{
    int qblk = (int)gridDim.x - 1 - (int)blockIdx.x;   // heavy blocks first
    int h    = blockIdx.y;
    int b    = blockIdx.z;
    int kvh  = h >> 2;
    int tid  = threadIdx.x;
    int wv   = tid >> 6;
    int lane = tid & 63;
    int l15  = lane & 15;
    int l4   = lane >> 4;
    int q0   = qblk * 128;
    int qw   = q0 + wv * 32;

    __shared__ unsigned short Ks[64 * 64];    // [key][dim], swizzled chunks
    __shared__ unsigned short Vts[64 * 64];   // [dim][key], swizzled chunks
    __shared__ unsigned short Pb[4][32][76];  // per-wave P tile
    __shared__ int kdoc[64];

    const unsigned short* qus = reinterpret_cast<const unsigned short*>(qkv);
    const unsigned short* kus = qus + 2048;

    bf16x8 aq[2][2];
    #pragma unroll
    for (int qt = 0; qt < 2; ++qt) {
        const unsigned short* qrow = qus + (size_t)(b * SEQ + qw + qt * 16 + l15) * QKVS + h * HDD;
        aq[qt][0] = *reinterpret_cast<const bf16x8*>(qrow + l4 * 8);
        aq[qt][1] = *reinterpret_cast<const bf16x8*>(qrow + 32 + l4 * 8);
    }
    int qd[2][4];
    #pragma unroll
    for (int qt = 0; qt < 2; ++qt)
        #pragma unroll
        for (int r = 0; r < 4; ++r)
            qd[qt][r] = doc[b * SEQ + qw + qt * 16 + l4 * 4 + r];
    int qd_w   = doc[b * SEQ + qw];
    int qd_blk = doc[b * SEQ + q0];

    float mrow[2][4], lrow[2][4];
    #pragma unroll
    for (int qt = 0; qt < 2; ++qt)
        #pragma unroll
        for (int r = 0; r < 4; ++r) { mrow[qt][r] = -1e30f; lrow[qt][r] = 0.f; }
    floatx4 accO[2][4] = {};

    int slot0 = tid, slot1 = tid + 256;
    int row0 = slot0 >> 3, g0 = (slot0 & 7) ^ (row0 & 7);
    int row1 = slot1 >> 3, g1 = (slot1 & 7) ^ (row1 & 7);
    const unsigned short* vtb = vT + ((size_t)(b * NKVV + kvh) * 64) * SEQ;

    int kc_end = 2 * qblk + 1;
    for (int kc = 0; kc <= kc_end; ++kc) {
        int k0 = kc * 64;
        int kd_last = doc[b * SEQ + k0 + 63];
        if (kd_last < qd_blk) continue;        // block-uniform doc skip

        __syncthreads();
        __builtin_amdgcn_global_load_lds(
            (gas_ptr)(kus + (size_t)(b * SEQ + k0 + row0) * QKVS + kvh * HDD + g0 * 8),
            (las_ptr)(Ks + slot0 * 8), 16, 0, 0);
        __builtin_amdgcn_global_load_lds(
            (gas_ptr)(kus + (size_t)(b * SEQ + k0 + row1) * QKVS + kvh * HDD + g1 * 8),
            (las_ptr)(Ks + slot1 * 8), 16, 0, 0);
        __builtin_amdgcn_global_load_lds(
            (gas_ptr)(vtb + (size_t)row0 * SEQ + k0 + g0 * 8),
            (las_ptr)(Vts + slot0 * 8), 16, 0, 0);
        __builtin_amdgcn_global_load_lds(
            (gas_ptr)(vtb + (size_t)row1 * SEQ + k0 + g1 * 8),
            (las_ptr)(Vts + slot1 * 8), 16, 0, 0);
        if (tid < 64) kdoc[tid] = doc[b * SEQ + k0 + tid];
        __syncthreads();

        if (k0 <= qw + 31 && kd_last >= qd_w) {   // wave-uniform compute skip
            #pragma unroll
            for (int qt = 0; qt < 2; ++qt) {
                float s[4][4];
                #pragma unroll
                for (int t = 0; t < 4; ++t) {
                    int krow = t * 16 + l15;
                    bf16x8 bk0 = *reinterpret_cast<const bf16x8*>(Ks + krow * 64 + ((l4 ^ (krow & 7)) * 8));
                    bf16x8 bk1 = *reinterpret_cast<const bf16x8*>(Ks + krow * 64 + ((((l4 + 4)) ^ (krow & 7)) * 8));
                    floatx4 acc = {};
                    acc = __builtin_amdgcn_mfma_f32_16x16x32_bf16(aq[qt][0], bk0, acc, 0, 0, 0);
                    acc = __builtin_amdgcn_mfma_f32_16x16x32_bf16(aq[qt][1], bk1, acc, 0, 0, 0);
                    int key = k0 + krow;
                    int kd  = kdoc[krow];
                    #pragma unroll
                    for (int r = 0; r < 4; ++r) {
                        int qrow = qw + qt * 16 + l4 * 4 + r;
                        bool valid = (kd == qd[qt][r]) && (key <= qrow);
                        s[t][r] = valid ? acc[r] * 0.125f : -1e30f;
                    }
                }
                #pragma unroll
                for (int r = 0; r < 4; ++r) {
                    float pm = fmaxf(fmaxf(s[0][r], s[1][r]), fmaxf(s[2][r], s[3][r]));
                    pm = fmaxf(pm, __shfl_xor(pm, 1));
                    pm = fmaxf(pm, __shfl_xor(pm, 2));
                    pm = fmaxf(pm, __shfl_xor(pm, 4));
                    pm = fmaxf(pm, __shfl_xor(pm, 8));
                    float mnew = fmaxf(mrow[qt][r], pm);
                    float alpha = __expf(mrow[qt][r] - mnew);
                    mrow[qt][r] = mnew;
                    float ps = 0.f;
                    #pragma unroll
                    for (int t = 0; t < 4; ++t) {
                        float p = (s[t][r] <= -1e29f) ? 0.f : __expf(s[t][r] - mnew);
                        Pb[wv][qt * 16 + l4 * 4 + r][t * 16 + l15] = f2bu(p);
                        ps += p;
                    }
                    ps += __shfl_xor(ps, 1);
                    ps += __shfl_xor(ps, 2);
                    ps += __shfl_xor(ps, 4);
                    ps += __shfl_xor(ps, 8);
                    lrow[qt][r] = lrow[qt][r] * alpha + ps;
                    #pragma unroll
                    for (int t = 0; t < 4; ++t) accO[qt][t][r] *= alpha;
                }
            }
            #pragma unroll
            for (int qt = 0; qt < 2; ++qt) {
                bf16x8 ap0 = *reinterpret_cast<const bf16x8*>(&Pb[wv][qt * 16 + l15][l4 * 8]);
                bf16x8 ap1 = *reinterpret_cast<const bf16x8*>(&Pb[wv][qt * 16 + l15][32 + l4 * 8]);
                #pragma unroll
                for (int t = 0; t < 4; ++t) {
                    int vrow = t * 16 + l15;
                    bf16x8 bv0 = *reinterpret_cast<const bf16x8*>(Vts + vrow * 64 + ((l4 ^ (vrow & 7)) * 8));
                    bf16x8 bv1 = *reinterpret_cast<const bf16x8*>(Vts + vrow * 64 + ((((l4 + 4)) ^ (vrow & 7)) * 8));
                    accO[qt][t] = __builtin_amdgcn_mfma_f32_16x16x32_bf16(ap0, bv0, accO[qt][t], 0, 0, 0);
                    accO[qt][t] = __builtin_amdgcn_mfma_f32_16x16x32_bf16(ap1, bv1, accO[qt][t], 0, 0, 0);
                }
            }
        }
    }

    #pragma unroll
    for (int qt = 0; qt < 2; ++qt)
        #pragma unroll
        for (int r = 0; r < 4; ++r) {
            float inv = 1.0f / lrow[qt][r];
            size_t base = (size_t)(b * SEQ + qw + qt * 16 + l4 * 4 + r) * (NHH * HDD) + h * HDD;
            #pragma unroll
            for (int t = 0; t < 4; ++t)
                ob[base + t * 16 + l15] = __float2bfloat16(accO[qt][t][r] * inv);
        }
}

// ---------------------------------------------------------------------------
extern "C" void kernel_launch(void* const* d_in, const int* in_sizes, int n_in,
                              void* d_out, int out_size, void* d_ws, size_t ws_size,
                              hipStream_t stream) {
    const float* x  = (const float*)d_in[0];
    const float* rc = (const float*)d_in[1];
    const float* rs = (const float*)d_in[2];
    const int*   dc = (const int*)d_in[3];
    const float* Wq = (const float*)d_in[4];
    const float* Wk = (const float*)d_in[5];
    const float* Wv = (const float*)d_in[6];
    const float* Wo = (const float*)d_in[7];
    float* out = (float*)d_out;

    const int M   = BB * SEQ;        // 4096
    const int KVD = NKVV * HDD;      // 512
    const int QKVN = DIMD + 2 * KVD; // 3072

    char* ws = (char*)d_ws;
    size_t off = 0;
    auto alloc = [&](size_t elems) { __hip_bfloat16* p = (__hip_bfloat16*)(ws + off); off += elems * 2; return p; };
    __hip_bfloat16* xb   = alloc((size_t)M * DIMD);      // 16 MB
    __hip_bfloat16* wqkv = alloc((size_t)QKVN * DIMD);   // 12 MB
    __hip_bfloat16* wob  = alloc((size_t)DIMD * DIMD);   //  8 MB
    __hip_bfloat16* qkv  = alloc((size_t)M * QKVN);      // 24 MB
    __hip_bfloat16* abuf = alloc((size_t)M * DIMD);      // 16 MB
    unsigned short* vtb  = (unsigned short*)alloc((size_t)BB * NKVV * HDD * SEQ); // 4 MB

    // one fused f32->bf16 conversion launch (18M elems, 4 per thread)
    {
        unsigned total4 = (C_X + C_WQ + C_WK + C_WV + C_WO) / 4;
        cvt_all<<<dim3((total4 + 255) / 256), 256, 0, stream>>>(
            x, Wq, Wk, Wv, Wo, xb, wqkv, wob);
    }

    // fused QKV projection with RoPE epilogue: [4096][3072]
    gemm_lds<__hip_bfloat16, true><<<dim3(M / 128, QKVN / 128), 256, 0, stream>>>(
        xb, wqkv, qkv, M, QKVN, DIMD, QKVN, rc, rs);

    // V transpose for PV B-fragments
    transpose_v<<<dim3(SEQ / 64, NKVV, BB), 256, 0, stream>>>(qkv, vtb);

    // attention (MFMA, doc-skip)
    attn_mfma<<<dim3(SEQ / 128, NHH, BB), 256, 0, stream>>>(qkv, vtb, dc, abuf);

    // output projection (f32 out)
    gemm_lds<float, false><<<dim3(M / 128, DIMD / 128), 256, 0, stream>>>(
        abuf, wob, out, M, DIMD, DIMD, DIMD, nullptr, nullptr);
}